// Round 8
// baseline (492.769 us; speedup 1.0000x reference)
//
#include <hip/hip_runtime.h>

// 3-layer LSTM, B=4096, T=336, F=12, H=50, fp32 in/out.
// MFMA: z^T = W'(gate-permuted, gate-prescaled) @ a^T via mfma_f32_16x16x32_f16.
// R = 4*unit + gate -> each lane's 4 accumulators = 4 gates of one unit ->
// lane-local c/h update; c in registers; weights in VGPRs (loaded once).
// Layer-specialized waves (R6) + VECTOR-CLOCK dataflow (R8): per-wave LDS
// progress slots (wrprog/rdprog[16], single-writer) replace R7's sum counters,
// whose sum-threshold admitted skew races (fast waves masking laggards ->
// one-tick-stale reads, absmax 2.4e-3). Waits are exact minima over static
// wave masks -> no barrier lockstep convoy, no race. Deadlock-free: tick-tau
// waits reference only tick-(tau-1) completions (induction).

#define Bsz 4096
#define Tt  336
#define BT  16
#define NTH 1024

typedef _Float16 half8 __attribute__((ext_vector_type(8)));
typedef float    floatx4 __attribute__((ext_vector_type(4)));

// act0 row: 64 halfs = 8 chunks (16B). [x 0..11 | h0 12..61 | pad]
// act1/2 row: 128 halfs = 16 chunks. [h_in 0..49 | h_self 50..99 | pad]
// XOR-chunk swizzle: chunk c of row n stored at c ^ (n & (nchunks-1)).
struct __align__(16) SMem {
  _Float16 act0[2][BT * 64];
  _Float16 act1[2][BT * 128];
  _Float16 act2[2][BT * 128];
};  // 20480 B

__device__ __forceinline__ int offA0(int n, int L) {
  return n * 64 + ((((L >> 3) ^ n) & 7) << 3) + (L & 7);
}
__device__ __forceinline__ int offA12(int n, int L) {
  return n * 128 + ((((L >> 3) ^ n) & 15) << 3) + (L & 7);
}

// z gate-prescaled: gates i,f,o hold -log2(e)*z ; gate g holds 2*log2(e)*z.
__device__ __forceinline__ float lstm_cell(floatx4 z, float& c) {
  float ei = __builtin_amdgcn_exp2f(z[0]);
  float ef = __builtin_amdgcn_exp2f(z[1]);
  float eg = __builtin_amdgcn_exp2f(z[2]);
  float eo = __builtin_amdgcn_exp2f(z[3]);
  float ig = __builtin_amdgcn_rcpf(1.f + ei);   // sigmoid(i)
  float fg = __builtin_amdgcn_rcpf(1.f + ef);   // sigmoid(f)
  float rg = __builtin_amdgcn_rcpf(1.f + eg);
  float og = __builtin_amdgcn_rcpf(1.f + eo);   // sigmoid(o)
  float gg = 1.f - 2.f * rg;                    // tanh(g)
  c = fg * c + ig * gg;
  float ec = __builtin_amdgcn_exp2f(2.885390082f * c);
  float rc = __builtin_amdgcn_rcpf(1.f + ec);
  return og * (1.f - 2.f * rc);                 // o * tanh(c)
}

// A-fragment (8 halfs) of gate-permuted, gate-prescaled weights.
__device__ __forceinline__ half8 wfrag(const float* __restrict__ Wih,
                                       const float* __restrict__ Whh,
                                       int lenih, int bound, int R, int k0) {
  half8 r = {};
  int u = R >> 2, g = R & 3;
  float sc = (g == 2) ? 2.885390082f : -1.442695041f;
  if (u < 50) {
    int row = g * 50 + u;
#pragma unroll
    for (int j = 0; j < 8; ++j) {
      int k = k0 + j;
      float v = 0.f;
      if (k < bound)           v = Wih[row * lenih + k];
      else if (k < bound + 50) v = Whh[row * 50 + (k - bound)];
      r[j] = (_Float16)(sc * v);
    }
  }
  return r;
}

// ---- vector-clock primitives (LDS, workgroup scope) ----
// wait until prog[i] >= need for every wave i in mask (exact, per-wave).
__device__ __forceinline__ void wait_all(int* prog, unsigned mask, int need, int lane) {
  bool mine = (lane < 16) && ((mask >> lane) & 1u);
  while (true) {
    int v = mine ? __hip_atomic_load(&prog[lane & 15], __ATOMIC_RELAXED,
                                     __HIP_MEMORY_SCOPE_WORKGROUP)
                 : 0x7fffffff;
    if (__all(v >= need)) break;
    __builtin_amdgcn_s_sleep(1);
  }
  asm volatile("" ::: "memory");   // keep protected LDS ops below the wait
}
// publish progress: prior LDS ops drained (lgkm only -- global x-prefetch
// deliberately stays in flight), then single-writer store.
__device__ __forceinline__ void store_prog(int* slot, int val, int lane) {
  asm volatile("s_waitcnt lgkmcnt(0)" ::: "memory");
  if (lane == 0)
    __hip_atomic_store(slot, val, __ATOMIC_RELAXED, __HIP_MEMORY_SCOPE_WORKGROUP);
}

#define MFMA(a, b, acc) __builtin_amdgcn_mfma_f32_16x16x32_f16((a), (b), (acc), 0, 0, 0)

// wave-group masks: L0={0,1,2,3,13} L1={4,5,6,7,14} L2={8,9,10,11,12,15}
#define MASK_L0   0x200Fu
#define MASK_L1   0x40F0u
#define MASK_L2   0x9F00u
#define MASK_L01  0x60FFu
#define MASK_L12  0xDFF0u

__global__ __launch_bounds__(NTH, 4)
void lstm_mfma_kernel(const float* __restrict__ x,
                      const float* __restrict__ Wih0, const float* __restrict__ Whh0,
                      const float* __restrict__ bih0, const float* __restrict__ bhh0,
                      const float* __restrict__ Wih1, const float* __restrict__ Whh1,
                      const float* __restrict__ bih1, const float* __restrict__ bhh1,
                      const float* __restrict__ Wih2, const float* __restrict__ Whh2,
                      const float* __restrict__ bih2, const float* __restrict__ bhh2,
                      const float* __restrict__ Wlin, const float* __restrict__ blin,
                      float* __restrict__ out) {
  __shared__ SMem sm;
  __shared__ int wrprog[16];   // wave w completed writes of ticks < wrprog[w]
  __shared__ int rdprog[16];   // wave w completed reads  of ticks < rdprog[w]
  const int tid  = threadIdx.x;
  const int blk  = blockIdx.x;
  const int lane = tid & 63;
  const int w    = tid >> 6;       // wave 0..15
  const int n    = lane & 15;      // batch col / A-row in tile
  const int q    = lane >> 4;      // quad

  // ---- zero LDS (h(-1)=0 for all layers/parities, pads=0) + clocks ----
  {
    int* zp = (int*)&sm;
    for (int i = tid; i < (int)(sizeof(SMem) / 4); i += NTH) zp[i] = 0;
  }
  if (tid < 16) { wrprog[tid] = 0; rdprog[tid] = 0; }

  // ---- wave -> (layer, cells); SIMD k hosts waves {k,k+4,k+8,k+12}:
  //      cells/SIMD = 9-10 ----
  int Lw, nc, mm3[3] = {0, 0, 0};
  switch (w) {
    case 0:  Lw = 0; nc = 3; mm3[0] = 0;  mm3[1] = 1;  mm3[2] = 2;  break;
    case 1:  Lw = 0; nc = 2; mm3[0] = 3;  mm3[1] = 4;               break;
    case 2:  Lw = 0; nc = 3; mm3[0] = 5;  mm3[1] = 6;  mm3[2] = 7;  break;
    case 3:  Lw = 0; nc = 2; mm3[0] = 8;  mm3[1] = 9;               break;
    case 4:  Lw = 1; nc = 2; mm3[0] = 0;  mm3[1] = 1;               break;
    case 5:  Lw = 1; nc = 3; mm3[0] = 2;  mm3[1] = 3;  mm3[2] = 4;  break;
    case 6:  Lw = 1; nc = 2; mm3[0] = 5;  mm3[1] = 6;               break;
    case 7:  Lw = 1; nc = 3; mm3[0] = 7;  mm3[1] = 8;  mm3[2] = 9;  break;
    case 8:  Lw = 2; nc = 3; mm3[0] = 0;  mm3[1] = 1;  mm3[2] = 2;  break;
    case 9:  Lw = 2; nc = 2; mm3[0] = 3;  mm3[1] = 4;               break;
    case 10: Lw = 2; nc = 2; mm3[0] = 5;  mm3[1] = 6;               break;
    case 11: Lw = 2; nc = 2; mm3[0] = 7;  mm3[1] = 8;               break;
    case 12: Lw = 2; nc = 2; mm3[0] = 9;  mm3[1] = 10;              break;
    case 13: Lw = 0; nc = 3; mm3[0] = 10; mm3[1] = 11; mm3[2] = 12; break;
    case 14: Lw = 1; nc = 3; mm3[0] = 10; mm3[1] = 11; mm3[2] = 12; break;
    default: Lw = 2; nc = 2; mm3[0] = 11; mm3[1] = 12;              break;
  }
  const float* Wih = (Lw == 0) ? Wih0 : ((Lw == 1) ? Wih1 : Wih2);
  const float* Whh = (Lw == 0) ? Whh0 : ((Lw == 1) ? Whh1 : Whh2);
  const float* bih = (Lw == 0) ? bih0 : ((Lw == 1) ? bih1 : bih2);
  const float* bhh = (Lw == 0) ? bhh0 : ((Lw == 1) ? bhh1 : bhh2);
  const int lenih = (Lw == 0) ? 12 : 50;
  const int nkc   = (Lw == 0) ? 2 : 4;

  // ---- per-cell weight fragments, biases, write offsets, c-state ----
  half8  af[3][4];
  floatx4 bia[3];
  float  cst[3] = {0.f, 0.f, 0.f};
  int    woA[3], woB[3];
  bool   uokk[3];
#pragma unroll
  for (int i = 0; i < 3; ++i) {
    bia[i] = (floatx4){0, 0, 0, 0};
#pragma unroll
    for (int kc = 0; kc < 4; ++kc) af[i][kc] = (half8){};
    int m = mm3[i];
    int u = 4 * m + q;
    int uc = (u < 50) ? u : 49;
    uokk[i] = (i < nc) && (u < 50);
    if (Lw == 0) { woA[i] = offA0 (n, 12 + uc); woB[i] = offA12(n, uc); }
    else         { woA[i] = offA12(n, 50 + uc); woB[i] = offA12(n, uc); }
    if (i < nc) {
      int R = 16 * m + n;
#pragma unroll
      for (int kc = 0; kc < 4; ++kc)
        if (kc < nkc)
          af[i][kc] = wfrag(Wih, Whh, lenih, lenih, R, kc * 32 + q * 8);
      if (u < 50) {
#pragma unroll
        for (int g = 0; g < 4; ++g) {
          float sc = (g == 2) ? 2.885390082f : -1.442695041f;
          bia[i][g] = sc * (bih[g * 50 + u] + bhh[g * 50 + u]);
        }
      }
    }
  }

  // ---- lane-constant LDS read offsets (halfs) ----
  const int ro0[2] = { offA0(n, q * 8), offA0(n, 32 + q * 8) };
  const int ro1[4] = { offA12(n, q * 8),      offA12(n, 32 + q * 8),
                       offA12(n, 64 + q * 8), offA12(n, 96 + q * 8) };

  // ---- x stager: tid<192 = waves 0..2 (all L0 waves), 16 rows x 12 feats ----
  const int sr = (tid < 192) ? tid / 12 : 0;
  const int sf = (tid < 192) ? tid - sr * 12 : 0;
  const int sxo = offA0(sr, sf);
  const float* xp = x + ((size_t)(blk * BT + sr) * Tt) * 12 + sf;
  float xnext = 0.f;

  __syncthreads();   // zero-fill + clock init visible
  if (tid < 192) {
    sm.act0[0][sxo] = (_Float16)xp[0];   // x(0) into parity-0 buffer
    xnext = xp[12];                      // x(1)
  }
  __syncthreads();

  // Tick TAU (parity p = TAU&1): read planes [p], write planes [1-p].
  // L0 active TAU<=335 (step TAU); L1 active 1<=TAU<=336 (step TAU-1);
  // L2 active TAU>=2 (step TAU-2). Inactive ticks advance clocks only.
  // Reader at TAU: all producers' wrprog >= TAU (their tick TAU-1 writes,
  // which produced plane [TAU&1], are done). Writer at TAU: all consumers'
  // rdprog >= TAU (their tick TAU-1 reads of plane [1-(TAU&1)] are done).
#define TICK(p, TAU, CHK)                                                   \
  {                                                                         \
    if (Lw == 0) {                                                          \
      if (!(CHK) || (TAU) <= 335) {                                         \
        wait_all(wrprog, MASK_L0, (TAU), lane);                             \
        half8 b0 = *(const half8*)&sm.act0[p][ro0[0]];                      \
        half8 b1 = *(const half8*)&sm.act0[p][ro0[1]];                      \
        store_prog(&rdprog[w], (TAU) + 1, lane);                            \
        float hv[3];                                                        \
        for (int i = 0; i < 3; ++i) if (i < nc) {                           \
          floatx4 z = bia[i];                                               \
          z = MFMA(af[i][0], b0, z);                                        \
          z = MFMA(af[i][1], b1, z);                                        \
          hv[i] = lstm_cell(z, cst[i]);                                     \
        }                                                                   \
        wait_all(rdprog, MASK_L01, (TAU), lane);                            \
        if (tid < 192 && (TAU) + 1 < Tt)                                    \
          sm.act0[1 - (p)][sxo] = (_Float16)xnext;                          \
        for (int i = 0; i < 3; ++i) if (uokk[i]) {                          \
          _Float16 hh = (_Float16)hv[i];                                    \
          sm.act0[1 - (p)][woA[i]] = hh;                                    \
          sm.act1[1 - (p)][woB[i]] = hh;                                    \
        }                                                                   \
        store_prog(&wrprog[w], (TAU) + 1, lane);                            \
        if (tid < 192)                                                      \
          xnext = ((TAU) + 2 < Tt) ? xp[((TAU) + 2) * 12] : 0.f;            \
      } else {                                                              \
        store_prog(&rdprog[w], (TAU) + 1, lane);                            \
        store_prog(&wrprog[w], (TAU) + 1, lane);                            \
      }                                                                     \
    } else if (Lw == 1) {                                                   \
      if (!(CHK) || ((TAU) >= 1 && (TAU) <= 336)) {                         \
        wait_all(wrprog, MASK_L01, (TAU), lane);                            \
        half8 b0 = *(const half8*)&sm.act1[p][ro1[0]];                      \
        half8 b1 = *(const half8*)&sm.act1[p][ro1[1]];                      \
        half8 b2 = *(const half8*)&sm.act1[p][ro1[2]];                      \
        half8 b3 = *(const half8*)&sm.act1[p][ro1[3]];                      \
        store_prog(&rdprog[w], (TAU) + 1, lane);                            \
        float hv[3];                                                        \
        for (int i = 0; i < 3; ++i) if (i < nc) {                           \
          floatx4 z = bia[i];                                               \
          z = MFMA(af[i][0], b0, z);                                        \
          z = MFMA(af[i][1], b1, z);                                        \
          z = MFMA(af[i][2], b2, z);                                        \
          z = MFMA(af[i][3], b3, z);                                        \
          hv[i] = lstm_cell(z, cst[i]);                                     \
        }                                                                   \
        wait_all(rdprog, MASK_L12, (TAU), lane);                            \
        for (int i = 0; i < 3; ++i) if (uokk[i]) {                          \
          _Float16 hh = (_Float16)hv[i];                                    \
          sm.act1[1 - (p)][woA[i]] = hh;                                    \
          sm.act2[1 - (p)][woB[i]] = hh;                                    \
        }                                                                   \
        store_prog(&wrprog[w], (TAU) + 1, lane);                            \
      } else {                                                              \
        store_prog(&rdprog[w], (TAU) + 1, lane);                            \
        store_prog(&wrprog[w], (TAU) + 1, lane);                            \
      }                                                                     \
    } else {                                                                \
      if (!(CHK) || ((TAU) >= 2)) {                                         \
        wait_all(wrprog, MASK_L12, (TAU), lane);                            \
        half8 b0 = *(const half8*)&sm.act2[p][ro1[0]];                      \
        half8 b1 = *(const half8*)&sm.act2[p][ro1[1]];                      \
        half8 b2 = *(const half8*)&sm.act2[p][ro1[2]];                      \
        half8 b3 = *(const half8*)&sm.act2[p][ro1[3]];                      \
        store_prog(&rdprog[w], (TAU) + 1, lane);                            \
        float hv[3];                                                        \
        for (int i = 0; i < 3; ++i) if (i < nc) {                           \
          floatx4 z = bia[i];                                               \
          z = MFMA(af[i][0], b0, z);                                        \
          z = MFMA(af[i][1], b1, z);                                        \
          z = MFMA(af[i][2], b2, z);                                        \
          z = MFMA(af[i][3], b3, z);                                        \
          hv[i] = lstm_cell(z, cst[i]);                                     \
        }                                                                   \
        wait_all(rdprog, MASK_L2, (TAU), lane);                             \
        for (int i = 0; i < 3; ++i) if (uokk[i])                            \
          sm.act2[1 - (p)][woA[i]] = (_Float16)hv[i];                       \
        store_prog(&wrprog[w], (TAU) + 1, lane);                            \
      } else {                                                              \
        store_prog(&rdprog[w], (TAU) + 1, lane);                            \
        store_prog(&wrprog[w], (TAU) + 1, lane);                            \
      }                                                                     \
    }                                                                       \
  }

  // fill (literal TAU -> activity folds at compile time)
  TICK(0, 0, 1)
  TICK(1, 1, 1)
  // steady: ticks 2..335
#pragma unroll 1
  for (int t = 2; t < Tt; t += 2) {
    TICK(0, t, 0)
    TICK(1, t + 1, 0)
  }
  // drain
  TICK(0, 336, 1)
  TICK(1, 337, 1)
#undef TICK

  __syncthreads();

  // ---- epilogue: out[r] = b_lin + h2(335) . W_lin ----
  // L2 step 335 ran at tick 337 -> wrote plane act2[0]
  if (tid < BT) {
    float s = blin[0];
    for (int uu = 0; uu < 50; ++uu)
      s += Wlin[uu] * (float)sm.act2[0][offA12(tid, 50 + uu)];
    out[blk * BT + tid] = s;
  }
}

extern "C" void kernel_launch(void* const* d_in, const int* in_sizes, int n_in,
                              void* d_out, int out_size, void* d_ws, size_t ws_size,
                              hipStream_t stream) {
  const float* x    = (const float*)d_in[0];
  const float* Wih0 = (const float*)d_in[1];
  const float* Whh0 = (const float*)d_in[2];
  const float* bih0 = (const float*)d_in[3];
  const float* bhh0 = (const float*)d_in[4];
  const float* Wih1 = (const float*)d_in[5];
  const float* Whh1 = (const float*)d_in[6];
  const float* bih1 = (const float*)d_in[7];
  const float* bhh1 = (const float*)d_in[8];
  const float* Wih2 = (const float*)d_in[9];
  const float* Whh2 = (const float*)d_in[10];
  const float* bih2 = (const float*)d_in[11];
  const float* bhh2 = (const float*)d_in[12];
  const float* Wlin = (const float*)d_in[13];
  const float* blin = (const float*)d_in[14];
  float* outp = (float*)d_out;

  dim3 grid(Bsz / BT);   // 256 blocks, 1 per CU
  dim3 block(NTH);       // 16 waves -> 4 per SIMD
  lstm_mfma_kernel<<<grid, block, 0, stream>>>(
      x, Wih0, Whh0, bih0, bhh0, Wih1, Whh1, bih1, bhh1,
      Wih2, Whh2, bih2, bhh2, Wlin, blin, outp);
}

// Round 9
// 415.637 us; speedup vs baseline: 1.1856x; 1.1856x over previous
//
#include <hip/hip_runtime.h>

// 3-layer LSTM, B=4096, T=336, F=12, H=50, fp32 in/out.
// MFMA: z^T = W'(gate-permuted, gate-prescaled) @ a^T via mfma_f32_16x16x32_f16.
// R = 4*unit + gate -> each lane's 4 accumulators = 4 gates of one unit ->
// lane-local c/h update; c in registers; weights in VGPRs (loaded once).
// Layer-specialized waves (R6: each wave owns 2-3 (tile,layer) cells of ONE
// layer -> reads one activation plane; layers skewed in time: at tick tau,
// L0 does step tau, L1 step tau-1, L2 step tau-2; one barrier per tick).
// R9: the tick barrier is LGKM-ONLY (asm s_waitcnt lgkmcnt(0); s_barrier).
// __syncthreads' vmcnt(0) was force-draining the stager's global x-prefetch
// (~900 cyc HBM latency exposed to all 16 waves every tick). All cross-wave
// data flows through LDS, so lgkmcnt(0) alone is sufficient; the x-load's
// result is consumed via a compiler-inserted vmcnt wait at its LDS store,
// now 2 ticks (distance-2 prefetch xn1/xn2) after issue.

#define Bsz 4096
#define Tt  336
#define BT  16
#define NTH 1024

typedef _Float16 half8 __attribute__((ext_vector_type(8)));
typedef float    floatx4 __attribute__((ext_vector_type(4)));

// act0 row: 64 halfs = 8 chunks (16B). [x 0..11 | h0 12..61 | pad]
// act1/2 row: 128 halfs = 16 chunks. [h_in 0..49 | h_self 50..99 | pad]
// XOR-chunk swizzle: chunk c of row n stored at c ^ (n & (nchunks-1)).
struct __align__(16) SMem {
  _Float16 act0[2][BT * 64];
  _Float16 act1[2][BT * 128];
  _Float16 act2[2][BT * 128];
};  // 20480 B

__device__ __forceinline__ int offA0(int n, int L) {
  return n * 64 + ((((L >> 3) ^ n) & 7) << 3) + (L & 7);
}
__device__ __forceinline__ int offA12(int n, int L) {
  return n * 128 + ((((L >> 3) ^ n) & 15) << 3) + (L & 7);
}

// Workgroup barrier draining ONLY LDS ops (not global/vmcnt).
__device__ __forceinline__ void barrier_lgkm() {
  asm volatile("s_waitcnt lgkmcnt(0)\n\ts_barrier" ::: "memory");
}

// z gate-prescaled: gates i,f,o hold -log2(e)*z ; gate g holds 2*log2(e)*z.
__device__ __forceinline__ float lstm_cell(floatx4 z, float& c) {
  float ei = __builtin_amdgcn_exp2f(z[0]);
  float ef = __builtin_amdgcn_exp2f(z[1]);
  float eg = __builtin_amdgcn_exp2f(z[2]);
  float eo = __builtin_amdgcn_exp2f(z[3]);
  float ig = __builtin_amdgcn_rcpf(1.f + ei);   // sigmoid(i)
  float fg = __builtin_amdgcn_rcpf(1.f + ef);   // sigmoid(f)
  float rg = __builtin_amdgcn_rcpf(1.f + eg);
  float og = __builtin_amdgcn_rcpf(1.f + eo);   // sigmoid(o)
  float gg = 1.f - 2.f * rg;                    // tanh(g)
  c = fg * c + ig * gg;
  float ec = __builtin_amdgcn_exp2f(2.885390082f * c);
  float rc = __builtin_amdgcn_rcpf(1.f + ec);
  return og * (1.f - 2.f * rc);                 // o * tanh(c)
}

// A-fragment (8 halfs) of gate-permuted, gate-prescaled weights.
__device__ __forceinline__ half8 wfrag(const float* __restrict__ Wih,
                                       const float* __restrict__ Whh,
                                       int lenih, int bound, int R, int k0) {
  half8 r = {};
  int u = R >> 2, g = R & 3;
  float sc = (g == 2) ? 2.885390082f : -1.442695041f;
  if (u < 50) {
    int row = g * 50 + u;
#pragma unroll
    for (int j = 0; j < 8; ++j) {
      int k = k0 + j;
      float v = 0.f;
      if (k < bound)           v = Wih[row * lenih + k];
      else if (k < bound + 50) v = Whh[row * 50 + (k - bound)];
      r[j] = (_Float16)(sc * v);
    }
  }
  return r;
}

#define MFMA(a, b, acc) __builtin_amdgcn_mfma_f32_16x16x32_f16((a), (b), (acc), 0, 0, 0)

__global__ __launch_bounds__(NTH, 4)
void lstm_mfma_kernel(const float* __restrict__ x,
                      const float* __restrict__ Wih0, const float* __restrict__ Whh0,
                      const float* __restrict__ bih0, const float* __restrict__ bhh0,
                      const float* __restrict__ Wih1, const float* __restrict__ Whh1,
                      const float* __restrict__ bih1, const float* __restrict__ bhh1,
                      const float* __restrict__ Wih2, const float* __restrict__ Whh2,
                      const float* __restrict__ bih2, const float* __restrict__ bhh2,
                      const float* __restrict__ Wlin, const float* __restrict__ blin,
                      float* __restrict__ out) {
  __shared__ SMem sm;
  const int tid  = threadIdx.x;
  const int blk  = blockIdx.x;
  const int lane = tid & 63;
  const int w    = tid >> 6;       // wave 0..15
  const int n    = lane & 15;      // batch col / A-row in tile
  const int q    = lane >> 4;      // quad

  // ---- zero LDS (h(-1)=0 for all layers/parities, pads=0) ----
  {
    int* zp = (int*)&sm;
    for (int i = tid; i < (int)(sizeof(SMem) / 4); i += NTH) zp[i] = 0;
  }

  // ---- wave -> (layer, cells); SIMD k hosts waves {k,k+4,k+8,k+12}:
  //      cells/SIMD = 9-10 ----
  int Lw, nc, mm3[3] = {0, 0, 0};
  switch (w) {
    case 0:  Lw = 0; nc = 3; mm3[0] = 0;  mm3[1] = 1;  mm3[2] = 2;  break;
    case 1:  Lw = 0; nc = 2; mm3[0] = 3;  mm3[1] = 4;               break;
    case 2:  Lw = 0; nc = 3; mm3[0] = 5;  mm3[1] = 6;  mm3[2] = 7;  break;
    case 3:  Lw = 0; nc = 2; mm3[0] = 8;  mm3[1] = 9;               break;
    case 4:  Lw = 1; nc = 2; mm3[0] = 0;  mm3[1] = 1;               break;
    case 5:  Lw = 1; nc = 3; mm3[0] = 2;  mm3[1] = 3;  mm3[2] = 4;  break;
    case 6:  Lw = 1; nc = 2; mm3[0] = 5;  mm3[1] = 6;               break;
    case 7:  Lw = 1; nc = 3; mm3[0] = 7;  mm3[1] = 8;  mm3[2] = 9;  break;
    case 8:  Lw = 2; nc = 3; mm3[0] = 0;  mm3[1] = 1;  mm3[2] = 2;  break;
    case 9:  Lw = 2; nc = 2; mm3[0] = 3;  mm3[1] = 4;               break;
    case 10: Lw = 2; nc = 2; mm3[0] = 5;  mm3[1] = 6;               break;
    case 11: Lw = 2; nc = 2; mm3[0] = 7;  mm3[1] = 8;               break;
    case 12: Lw = 2; nc = 2; mm3[0] = 9;  mm3[1] = 10;              break;
    case 13: Lw = 0; nc = 3; mm3[0] = 10; mm3[1] = 11; mm3[2] = 12; break;
    case 14: Lw = 1; nc = 3; mm3[0] = 10; mm3[1] = 11; mm3[2] = 12; break;
    default: Lw = 2; nc = 2; mm3[0] = 11; mm3[1] = 12;              break;
  }
  const float* Wih = (Lw == 0) ? Wih0 : ((Lw == 1) ? Wih1 : Wih2);
  const float* Whh = (Lw == 0) ? Whh0 : ((Lw == 1) ? Whh1 : Whh2);
  const float* bih = (Lw == 0) ? bih0 : ((Lw == 1) ? bih1 : bih2);
  const float* bhh = (Lw == 0) ? bhh0 : ((Lw == 1) ? bhh1 : bhh2);
  const int lenih = (Lw == 0) ? 12 : 50;
  const int nkc   = (Lw == 0) ? 2 : 4;

  // ---- per-cell weight fragments, biases, write offsets, c-state ----
  half8  af[3][4];
  floatx4 bia[3];
  float  cst[3] = {0.f, 0.f, 0.f};
  int    woA[3], woB[3];
  bool   uokk[3];
#pragma unroll
  for (int i = 0; i < 3; ++i) {
    bia[i] = (floatx4){0, 0, 0, 0};
#pragma unroll
    for (int kc = 0; kc < 4; ++kc) af[i][kc] = (half8){};
    int m = mm3[i];
    int u = 4 * m + q;
    int uc = (u < 50) ? u : 49;
    uokk[i] = (i < nc) && (u < 50);
    if (Lw == 0) { woA[i] = offA0 (n, 12 + uc); woB[i] = offA12(n, uc); }
    else         { woA[i] = offA12(n, 50 + uc); woB[i] = offA12(n, uc); }
    if (i < nc) {
      int R = 16 * m + n;
#pragma unroll
      for (int kc = 0; kc < 4; ++kc)
        if (kc < nkc)
          af[i][kc] = wfrag(Wih, Whh, lenih, lenih, R, kc * 32 + q * 8);
      if (u < 50) {
#pragma unroll
        for (int g = 0; g < 4; ++g) {
          float sc = (g == 2) ? 2.885390082f : -1.442695041f;
          bia[i][g] = sc * (bih[g * 50 + u] + bhh[g * 50 + u]);
        }
      }
    }
  }

  // ---- lane-constant LDS read offsets (halfs) ----
  const int ro0[2] = { offA0(n, q * 8), offA0(n, 32 + q * 8) };
  const int ro1[4] = { offA12(n, q * 8),      offA12(n, 32 + q * 8),
                       offA12(n, 64 + q * 8), offA12(n, 96 + q * 8) };

  // ---- x stager: tid<192 = waves 0..2 (all L0 waves), 16 rows x 12 feats.
  //      Distance-2 prefetch: at tick TAU, xn1 = x(TAU+1), xn2 = x(TAU+2);
  //      the LDS store of xn1 waits (compiler vmcnt) on a load issued 2
  //      ticks earlier -> HBM latency fully hidden under lgkm-only barriers.
  const int sr = (tid < 192) ? tid / 12 : 0;
  const int sf = (tid < 192) ? tid - sr * 12 : 0;
  const int sxo = offA0(sr, sf);
  const float* xp = x + ((size_t)(blk * BT + sr) * Tt) * 12 + sf;
  float xn1 = 0.f, xn2 = 0.f;

  __syncthreads();   // zero-fill visible
  if (tid < 192) {
    sm.act0[0][sxo] = (_Float16)xp[0];   // x(0) into parity-0 buffer
    xn1 = xp[12];                        // x(1)
    xn2 = xp[24];                        // x(2)
  }
  __syncthreads();

  // Tick TAU (parity p = TAU&1): read planes [p], write planes [1-p].
  // L0 active TAU<=335 (step TAU); L1 active 1<=TAU<=336 (step TAU-1);
  // L2 active TAU>=2 (step TAU-2). One lgkm-only barrier per tick.
#define TICK(p, TAU, CHK)                                                   \
  {                                                                         \
    if (tid < 192) {                                                        \
      if ((TAU) + 1 < Tt) sm.act0[1 - (p)][sxo] = (_Float16)xn1;            \
      xn1 = xn2;                                                            \
      xn2 = ((TAU) + 3 < Tt) ? xp[((TAU) + 3) * 12] : 0.f;                  \
    }                                                                       \
    if (Lw == 0) {                                                          \
      if (!(CHK) || (TAU) <= 335) {                                         \
        half8 b0 = *(const half8*)&sm.act0[p][ro0[0]];                      \
        half8 b1 = *(const half8*)&sm.act0[p][ro0[1]];                      \
        for (int i = 0; i < 3; ++i) if (i < nc) {                           \
          floatx4 z = bia[i];                                               \
          z = MFMA(af[i][0], b0, z);                                        \
          z = MFMA(af[i][1], b1, z);                                        \
          float h = lstm_cell(z, cst[i]);                                   \
          _Float16 hh = (_Float16)h;                                        \
          if (uokk[i]) { sm.act0[1 - (p)][woA[i]] = hh;                     \
                         sm.act1[1 - (p)][woB[i]] = hh; }                   \
        }                                                                   \
      }                                                                     \
    } else if (Lw == 1) {                                                   \
      if (!(CHK) || ((TAU) >= 1 && (TAU) <= 336)) {                         \
        half8 b0 = *(const half8*)&sm.act1[p][ro1[0]];                      \
        half8 b1 = *(const half8*)&sm.act1[p][ro1[1]];                      \
        half8 b2 = *(const half8*)&sm.act1[p][ro1[2]];                      \
        half8 b3 = *(const half8*)&sm.act1[p][ro1[3]];                      \
        for (int i = 0; i < 3; ++i) if (i < nc) {                           \
          floatx4 z = bia[i];                                               \
          z = MFMA(af[i][0], b0, z);                                        \
          z = MFMA(af[i][1], b1, z);                                        \
          z = MFMA(af[i][2], b2, z);                                        \
          z = MFMA(af[i][3], b3, z);                                        \
          float h = lstm_cell(z, cst[i]);                                   \
          _Float16 hh = (_Float16)h;                                        \
          if (uokk[i]) { sm.act1[1 - (p)][woA[i]] = hh;                     \
                         sm.act2[1 - (p)][woB[i]] = hh; }                   \
        }                                                                   \
      }                                                                     \
    } else {                                                                \
      if (!(CHK) || ((TAU) >= 2)) {                                         \
        half8 b0 = *(const half8*)&sm.act2[p][ro1[0]];                      \
        half8 b1 = *(const half8*)&sm.act2[p][ro1[1]];                      \
        half8 b2 = *(const half8*)&sm.act2[p][ro1[2]];                      \
        half8 b3 = *(const half8*)&sm.act2[p][ro1[3]];                      \
        for (int i = 0; i < 3; ++i) if (i < nc) {                           \
          floatx4 z = bia[i];                                               \
          z = MFMA(af[i][0], b0, z);                                        \
          z = MFMA(af[i][1], b1, z);                                        \
          z = MFMA(af[i][2], b2, z);                                        \
          z = MFMA(af[i][3], b3, z);                                        \
          float h = lstm_cell(z, cst[i]);                                   \
          if (uokk[i]) sm.act2[1 - (p)][woA[i]] = (_Float16)h;              \
        }                                                                   \
      }                                                                     \
    }                                                                       \
    barrier_lgkm();                                                         \
  }

  // fill (literal TAU -> activity folds at compile time)
  TICK(0, 0, 1)
  TICK(1, 1, 1)
  // steady: ticks 2..335 (unroll-2 for literal parity)
#pragma unroll 1
  for (int t = 2; t < Tt; t += 2) {
    TICK(0, t, 0)
    TICK(1, t + 1, 0)
  }
  // drain
  TICK(0, 336, 1)
  TICK(1, 337, 1)
#undef TICK

  __syncthreads();

  // ---- epilogue: out[r] = b_lin + h2(335) . W_lin ----
  // L2 step 335 ran at tick 337 -> wrote plane act2[0]
  if (tid < BT) {
    float s = blin[0];
    for (int uu = 0; uu < 50; ++uu)
      s += Wlin[uu] * (float)sm.act2[0][offA12(tid, 50 + uu)];
    out[blk * BT + tid] = s;
  }
}

extern "C" void kernel_launch(void* const* d_in, const int* in_sizes, int n_in,
                              void* d_out, int out_size, void* d_ws, size_t ws_size,
                              hipStream_t stream) {
  const float* x    = (const float*)d_in[0];
  const float* Wih0 = (const float*)d_in[1];
  const float* Whh0 = (const float*)d_in[2];
  const float* bih0 = (const float*)d_in[3];
  const float* bhh0 = (const float*)d_in[4];
  const float* Wih1 = (const float*)d_in[5];
  const float* Whh1 = (const float*)d_in[6];
  const float* bih1 = (const float*)d_in[7];
  const float* bhh1 = (const float*)d_in[8];
  const float* Wih2 = (const float*)d_in[9];
  const float* Whh2 = (const float*)d_in[10];
  const float* bih2 = (const float*)d_in[11];
  const float* bhh2 = (const float*)d_in[12];
  const float* Wlin = (const float*)d_in[13];
  const float* blin = (const float*)d_in[14];
  float* outp = (float*)d_out;

  dim3 grid(Bsz / BT);   // 256 blocks, 1 per CU
  dim3 block(NTH);       // 16 waves -> 4 per SIMD
  lstm_mfma_kernel<<<grid, block, 0, stream>>>(
      x, Wih0, Whh0, bih0, bhh0, Wih1, Whh1, bih1, bhh1,
      Wih2, Whh2, bih2, bhh2, Wlin, blin, outp);
}